// Round 9
// baseline (146.940 us; speedup 1.0000x reference)
//
#include <hip/hip_runtime.h>
#include <hip/hip_bf16.h>

typedef __attribute__((ext_vector_type(4))) float f32x4_t;
typedef __attribute__((ext_vector_type(8))) short bf16x8_t;

__device__ __forceinline__ short f2bfs(float x) {
    union { __hip_bfloat16 h; short s; } u;
    u.h = __float2bfloat16(x);   // RNE
    return u.s;
}

// ---------------------------------------------------------------------------
// Kernel 1: build fused 512x512 operator M in fragment-major bf16 layout.
//   c = m*32+o (output col of GEMM), k = n2*32+f (contraction index)
//   M[c][k] = diag[m] * sum_{n,m2} basis[m,n] * Wbig[o,n,f,m2] * basis[n2,m2]
// B-fragment layout for mfma_f32_16x16x32_bf16:
//   flat ushort idx = ((ks*32 + c16)*64 + lane)*8 + j
//   value = M[c16*16 + (lane&15)][ks*32 + (lane>>4)*8 + j]
// ---------------------------------------------------------------------------
__global__ void build_M_kernel(const float* __restrict__ basis,
                               const float* __restrict__ adj,
                               const float* __restrict__ e,
                               const float* __restrict__ We,
                               const float* __restrict__ W2,
                               const float* __restrict__ W3,
                               unsigned short* __restrict__ Mfrag) {
    const int t = blockIdx.x * blockDim.x + threadIdx.x;  // 0..262143
    const int c = t >> 9;           // 0..511
    const int k = t & 511;
    const int m  = c >> 5, o = c & 31;
    const int n2 = k >> 5, f = k & 31;

    float lv[16];
    float mx = -3.4e38f;
#pragma unroll
    for (int j = 0; j < 16; ++j) {
        float a = adj[m * 16 + j];
        float v = (a > 0.0f) ? e[m * 16 + j] : -9.0e15f;
        lv[j] = v;
        mx = fmaxf(mx, v);
    }
    float s = 0.0f;
#pragma unroll
    for (int j = 0; j < 16; ++j) s += expf(lv[j] - mx);
    const float dg = expf(lv[m] - mx) / s;

    float acc = 0.0f;
#pragma unroll
    for (int n = 0; n < 10; ++n) {
        float t2 = 0.0f;
#pragma unroll
        for (int m2 = 0; m2 < 10; ++m2)
            t2 += We[(o * 10 + n) * 320 + f * 10 + m2] * basis[n2 * 16 + m2];
        acc += basis[m * 16 + n] * t2;
    }
#pragma unroll
    for (int n = 0; n < 3; ++n) {
        float t2 = 0.0f;
#pragma unroll
        for (int m2 = 0; m2 < 3; ++m2)
            t2 += W2[(o * 3 + n) * 96 + f * 3 + m2] * basis[n2 * 16 + 10 + m2];
        acc += basis[m * 16 + 10 + n] * t2;
    }
#pragma unroll
    for (int n = 0; n < 3; ++n) {
        float t2 = 0.0f;
#pragma unroll
        for (int m2 = 0; m2 < 3; ++m2)
            t2 += W3[(o * 3 + n) * 96 + f * 3 + m2] * basis[n2 * 16 + 13 + m2];
        acc += basis[m * 16 + 13 + n] * t2;
    }

    const float Mv = dg * acc;

    const int ks = k >> 5;
    const int g  = (k >> 3) & 3;
    const int j  = k & 7;
    const int idx = ((ks * 32 + (c >> 4)) * 64 + ((c & 15) + 16 * g)) * 8 + j;
    Mfrag[idx] = (unsigned short)f2bfs(Mv);
}

// ---------------------------------------------------------------------------
// Kernel 2: Y[131072 x 512] = X[131072 x 512] @ M^T + bias
// Block: 512 threads (8 waves), BM=32 rows, grid 4096. Same staging/epilogue
// as R8's kernel H (bf16-frag LDS, cvt-once, 0-conflict; LDS-transpose
// epilogue). Change: explicit DEPTH-4 register pipeline on the B stream —
// bfr[4][4] slots, slot ks&3 reloaded for ks+4 right after its MFMAs, fully
// unrolled (static indices). Compiler then emits counted vmcnt waits: 4 KB
// of B per wave continuously in flight -> 16 waves/CU sustain the per-CU L2
// share instead of parking on full-latency stalls. A-frags prefetched
// 1-deep via ds_read. B prologue issues BEFORE __syncthreads so it drains
// during the staging barrier. LB(512,4) caps VGPR at 128 (budget ~120).
// ---------------------------------------------------------------------------
__global__ __launch_bounds__(512, 4)
void gemm_kernel(const float* __restrict__ X,
                 const unsigned short* __restrict__ Mfrag,
                 const float* __restrict__ bias,
                 float* __restrict__ Y) {
    __shared__ float lds_f32[8704];                // 34816 B
    unsigned short* Afrag = reinterpret_cast<unsigned short*>(lds_f32);

    const int tid  = threadIdx.x;
    const int lane = tid & 63;
    const int wave = tid >> 6;        // 0..7
    const int l15  = lane & 15;
    const int g    = lane >> 4;       // 0..3
    const size_t rowbase = (size_t)blockIdx.x * 32;

    const int colbase = wave * 64;
    const unsigned short* bp = Mfrag + ((size_t)((colbase >> 4) * 64) + lane) * 8;

    // ---- Stage full-K A-tile as bf16 fragments (cvt once) ----
    {
        const float* xb = X + rowbase * 512;
#pragma unroll
        for (int i = 0; i < 4; ++i) {
            const int f   = wave * 4 + i;
            const int row = (f & 1) * 16 + l15;
            const int k0  = (f >> 1) * 32 + g * 8;
            const float* src = xb + (size_t)row * 512 + k0;
            f32x4_t v0 = *reinterpret_cast<const f32x4_t*>(src);
            f32x4_t v1 = *reinterpret_cast<const f32x4_t*>(src + 4);
            bf16x8_t bv;
#pragma unroll
            for (int j = 0; j < 4; ++j) {
                bv[j]     = f2bfs(v0[j]);
                bv[j + 4] = f2bfs(v1[j]);
            }
            *reinterpret_cast<bf16x8_t*>(&Afrag[((f * 64) + lane) * 8]) = bv;
        }
    }

    // ---- B prologue: slots 0..3 (ks=0..3), issued before the barrier ----
    bf16x8_t bfr[4][4];
#pragma unroll
    for (int s = 0; s < 4; ++s)
#pragma unroll
        for (int ni = 0; ni < 4; ++ni)
            bfr[s][ni] = *reinterpret_cast<const bf16x8_t*>(
                bp + (size_t)s * 16384 + ni * 512);

    __syncthreads();

    // ---- K-loop with depth-4 B pipeline + 1-deep A prefetch ----
    f32x4_t acc[2][4];
#pragma unroll
    for (int a = 0; a < 2; ++a)
#pragma unroll
        for (int b = 0; b < 4; ++b)
            acc[a][b] = (f32x4_t){0.f, 0.f, 0.f, 0.f};

    bf16x8_t afr[2][2];
#pragma unroll
    for (int mi = 0; mi < 2; ++mi)
        afr[0][mi] = *reinterpret_cast<const bf16x8_t*>(&Afrag[(mi * 64 + lane) * 8]);

#pragma unroll
    for (int ks = 0; ks < 16; ++ks) {
        const int slot = ks & 3;
        const int asl  = ks & 1;
        if (ks + 1 < 16) {
#pragma unroll
            for (int mi = 0; mi < 2; ++mi)
                afr[asl ^ 1][mi] = *reinterpret_cast<const bf16x8_t*>(
                    &Afrag[(((ks + 1) * 2 + mi) * 64 + lane) * 8]);
        }
#pragma unroll
        for (int mi = 0; mi < 2; ++mi)
#pragma unroll
            for (int ni = 0; ni < 4; ++ni)
                acc[mi][ni] = __builtin_amdgcn_mfma_f32_16x16x32_bf16(
                    afr[asl][mi], bfr[slot][ni], acc[mi][ni], 0, 0, 0);
        if (ks + 4 < 16) {
#pragma unroll
            for (int ni = 0; ni < 4; ++ni)
                bfr[slot][ni] = *reinterpret_cast<const bf16x8_t*>(
                    bp + (size_t)(ks + 4) * 16384 + ni * 512);
        }
    }

    __syncthreads();   // all Afrag reads done; reuse LDS as epilogue scratch

    // ---- Epilogue: per-wave private transpose (stride 68), NT stores ----
    constexpr int SW = 68;
    float* scr = lds_f32 + wave * (16 * SW);       // 1088 f32/wave
    const float b_lo = bias[l15];
    const float b_hi = bias[16 + l15];

#pragma unroll
    for (int mi = 0; mi < 2; ++mi) {
#pragma unroll
        for (int ni = 0; ni < 4; ++ni) {
            const float bb = (ni & 1) ? b_hi : b_lo;
#pragma unroll
            for (int r = 0; r < 4; ++r)
                scr[(g * 4 + r) * SW + ni * 16 + l15] = acc[mi][ni][r] + bb;
        }
#pragma unroll
        for (int it = 0; it < 4; ++it) {
            const int flat = it * 64 + lane;   // 0..255
            const int row  = flat >> 4;        // 0..15
            const int c4   = flat & 15;
            f32x4_t v = *reinterpret_cast<const f32x4_t*>(&scr[row * SW + c4 * 4]);
            float* yp = Y + (rowbase + mi * 16 + row) * 512 + colbase + c4 * 4;
            __builtin_nontemporal_store(v, reinterpret_cast<f32x4_t*>(yp));
        }
    }
}

extern "C" void kernel_launch(void* const* d_in, const int* in_sizes, int n_in,
                              void* d_out, int out_size, void* d_ws, size_t ws_size,
                              hipStream_t stream) {
    const float* x     = (const float*)d_in[0];
    const float* basis = (const float*)d_in[1];
    const float* adj   = (const float*)d_in[2];
    const float* e     = (const float*)d_in[3];
    const float* We    = (const float*)d_in[4];
    const float* W2    = (const float*)d_in[5];
    const float* W3    = (const float*)d_in[6];
    const float* bias  = (const float*)d_in[7];

    unsigned short* Mfrag = (unsigned short*)d_ws;  // 512 KB needed
    if (ws_size < 512u * 512u * 2u) return;

    const int Bsz = in_sizes[0] / 512;              // 131072
    build_M_kernel<<<512, 512, 0, stream>>>(basis, adj, e, We, W2, W3, Mfrag);
    gemm_kernel<<<Bsz / 32, 512, 0, stream>>>(x, Mfrag, bias, (float*)d_out);
}

// Round 10
// 145.274 us; speedup vs baseline: 1.0115x; 1.0115x over previous
//
#include <hip/hip_runtime.h>
#include <hip/hip_bf16.h>

typedef __attribute__((ext_vector_type(4))) float f32x4_t;
typedef __attribute__((ext_vector_type(8))) short bf16x8_t;

__device__ __forceinline__ short f2bfs(float x) {
    union { __hip_bfloat16 h; short s; } u;
    u.h = __float2bfloat16(x);   // RNE
    return u.s;
}

__device__ __forceinline__ void gload_lds16(const void* g, void* l) {
    __builtin_amdgcn_global_load_lds(
        (const __attribute__((address_space(1))) void*)g,
        (__attribute__((address_space(3))) void*)l, 16, 0, 0);
}

// ---------------------------------------------------------------------------
// Kernel 1: build fused 512x512 operator M in fragment-major bf16 layout.
//   c = m*32+o (output col of GEMM), k = n2*32+f (contraction index)
//   M[c][k] = diag[m] * sum_{n,m2} basis[m,n] * Wbig[o,n,f,m2] * basis[n2,m2]
// B-fragment layout for mfma_f32_16x16x32_bf16:
//   flat ushort idx = ((ks*32 + c16)*64 + lane)*8 + j
//   value = M[c16*16 + (lane&15)][ks*32 + (lane>>4)*8 + j]
// ---------------------------------------------------------------------------
__global__ void build_M_kernel(const float* __restrict__ basis,
                               const float* __restrict__ adj,
                               const float* __restrict__ e,
                               const float* __restrict__ We,
                               const float* __restrict__ W2,
                               const float* __restrict__ W3,
                               unsigned short* __restrict__ Mfrag) {
    const int t = blockIdx.x * blockDim.x + threadIdx.x;  // 0..262143
    const int c = t >> 9;           // 0..511
    const int k = t & 511;
    const int m  = c >> 5, o = c & 31;
    const int n2 = k >> 5, f = k & 31;

    float lv[16];
    float mx = -3.4e38f;
#pragma unroll
    for (int j = 0; j < 16; ++j) {
        float a = adj[m * 16 + j];
        float v = (a > 0.0f) ? e[m * 16 + j] : -9.0e15f;
        lv[j] = v;
        mx = fmaxf(mx, v);
    }
    float s = 0.0f;
#pragma unroll
    for (int j = 0; j < 16; ++j) s += expf(lv[j] - mx);
    const float dg = expf(lv[m] - mx) / s;

    float acc = 0.0f;
#pragma unroll
    for (int n = 0; n < 10; ++n) {
        float t2 = 0.0f;
#pragma unroll
        for (int m2 = 0; m2 < 10; ++m2)
            t2 += We[(o * 10 + n) * 320 + f * 10 + m2] * basis[n2 * 16 + m2];
        acc += basis[m * 16 + n] * t2;
    }
#pragma unroll
    for (int n = 0; n < 3; ++n) {
        float t2 = 0.0f;
#pragma unroll
        for (int m2 = 0; m2 < 3; ++m2)
            t2 += W2[(o * 3 + n) * 96 + f * 3 + m2] * basis[n2 * 16 + 10 + m2];
        acc += basis[m * 16 + 10 + n] * t2;
    }
#pragma unroll
    for (int n = 0; n < 3; ++n) {
        float t2 = 0.0f;
#pragma unroll
        for (int m2 = 0; m2 < 3; ++m2)
            t2 += W3[(o * 3 + n) * 96 + f * 3 + m2] * basis[n2 * 16 + 13 + m2];
        acc += basis[m * 16 + 13 + n] * t2;
    }

    const float Mv = dg * acc;

    const int ks = k >> 5;
    const int g  = (k >> 3) & 3;
    const int j  = k & 7;
    const int idx = ((ks * 32 + (c >> 4)) * 64 + ((c & 15) + 16 * g)) * 8 + j;
    Mfrag[idx] = (unsigned short)f2bfs(Mv);
}

// ---------------------------------------------------------------------------
// Kernel 2: Y[131072 x 512] = X[131072 x 512] @ M^T + bias
// Block: 512 threads (8 waves), BM=64, grid 2048, 1 block/CU (120 KB LDS).
// Fully async K-loop (T3/T4): per ks-slab t, A (64x32 f32, 8 KB, XOR-unit
// swizzled via per-lane DMA source) and B (512x32 frag-linear bf16, 32 KB,
// straight memcpy) are DMA'd by global_load_lds into 3-buffer rotations.
// Phase t: issue slab t+2 -> ds_read/cvt/16 MFMA on slab t -> vmcnt(5)
// (slab t+1 retired; t+2 STAYS in flight - never drain) -> raw s_barrier.
// Slab t+2 writes buf (t-1)%3, whose reads finished before barrier_t: safe.
// The DMA has no dest regs so the compiler cannot sink it (the R9 failure);
// vmcnt counting is HW-FIFO, not schedulable away.
// Epilogue: per-wave LDS transpose (stride 68) in the B region, NT stores.
// ---------------------------------------------------------------------------
__global__ __launch_bounds__(512)
void gemm_kernel(const float* __restrict__ X,
                 const unsigned short* __restrict__ Mfrag,
                 const float* __restrict__ bias,
                 float* __restrict__ Y) {
    __shared__ float lds_f32[30720];       // 120 KB total
    float* Abuf = lds_f32;                 // 3 x 2048 f32 (8 KB slabs)
    unsigned short* Bbuf = reinterpret_cast<unsigned short*>(lds_f32 + 6144); // 3 x 16384 us

    const int tid  = threadIdx.x;
    const int lane = tid & 63;
    const int wave = tid >> 6;        // 0..7
    const int l15  = lane & 15;
    const int g    = lane >> 4;       // 0..3
    const size_t rowbase = (size_t)blockIdx.x * 64;
    const int colbase = wave * 64;

    // A-DMA per-lane source: wave w stages rows w*8..w*8+7 of the slab.
    // lane l -> LDS f32 (uniform base + l*4): row = w*8 + (l>>3), phys unit = l&7.
    // Swizzle: logical unit = (l&7) ^ (row&7) = (l&7) ^ (l>>3)  (w*8 == 0 mod 8).
    const int arow = lane >> 3;                       // 0..7
    const int aunit = (lane & 7) ^ arow;              // swizzled source unit
    const float* asrc = X + (rowbase + wave * 8 + arow) * 512 + aunit * 4;
    // B-DMA per-lane source: frag f (=c16) of slab t lives at
    // Mfrag[t*16384 + f*512 + lane*8], identical to its LDS layout (memcpy).
    const unsigned short* bsrc = Mfrag + lane * 8;

    auto stage = [&](int t) {
        const int b = t % 3;
        gload_lds16(asrc + t * 32, Abuf + b * 2048 + wave * 256);
#pragma unroll
        for (int i = 0; i < 4; ++i) {
            const int f = wave * 4 + i;
            gload_lds16(bsrc + (size_t)t * 16384 + f * 512,
                        Bbuf + b * 16384 + f * 512);
        }
    };

    f32x4_t acc[4][4];
#pragma unroll
    for (int a = 0; a < 4; ++a)
#pragma unroll
        for (int b = 0; b < 4; ++b)
            acc[a][b] = (f32x4_t){0.f, 0.f, 0.f, 0.f};

    const int s = l15 & 7;            // row&7 for row = mi*16 + l15

    // ---- prologue: slabs 0,1 in flight; wait slab 0 only ----
    stage(0);
    stage(1);
    asm volatile("s_waitcnt vmcnt(5)" ::: "memory");
    asm volatile("s_barrier" ::: "memory");

    // ---- 16 async phases ----
#pragma unroll
    for (int t = 0; t < 16; ++t) {
        if (t + 2 < 16) stage(t + 2);

        const int b = t % 3;
        const float* Ab = Abuf + b * 2048;
        const unsigned short* Bb = Bbuf + b * 16384;

        bf16x8_t bfr[4], afr[4];
#pragma unroll
        for (int ni = 0; ni < 4; ++ni)
            bfr[ni] = *reinterpret_cast<const bf16x8_t*>(
                Bb + ((colbase >> 4) + ni) * 512 + lane * 8);
#pragma unroll
        for (int mi = 0; mi < 4; ++mi) {
            const int row = mi * 16 + l15;
            f32x4_t lo = *reinterpret_cast<const f32x4_t*>(
                Ab + row * 32 + ((g * 2) ^ s) * 4);
            f32x4_t hi = *reinterpret_cast<const f32x4_t*>(
                Ab + row * 32 + ((g * 2 + 1) ^ s) * 4);
#pragma unroll
            for (int j = 0; j < 4; ++j) {
                afr[mi][j]     = f2bfs(lo[j]);
                afr[mi][j + 4] = f2bfs(hi[j]);
            }
        }
#pragma unroll
        for (int mi = 0; mi < 4; ++mi)
#pragma unroll
            for (int ni = 0; ni < 4; ++ni)
                acc[mi][ni] = __builtin_amdgcn_mfma_f32_16x16x32_bf16(
                    afr[mi], bfr[ni], acc[mi][ni], 0, 0, 0);

        if (t < 14)       asm volatile("s_waitcnt vmcnt(5)" ::: "memory");
        else if (t == 14) asm volatile("s_waitcnt vmcnt(0)" ::: "memory");
        if (t < 15)       asm volatile("s_barrier" ::: "memory");
    }

    __syncthreads();   // phase-15 reads done everywhere; LDS reusable

    // ---- Epilogue: per-wave private transpose (stride 68) in B region ----
    constexpr int SW = 68;
    float* scr = lds_f32 + 6144 + wave * (16 * SW);   // 8 x 1088 f32 <= 96 KB region
    const float b_lo = bias[l15];
    const float b_hi = bias[16 + l15];

#pragma unroll
    for (int mi = 0; mi < 4; ++mi) {
#pragma unroll
        for (int ni = 0; ni < 4; ++ni) {
            const float bb = (ni & 1) ? b_hi : b_lo;
#pragma unroll
            for (int r = 0; r < 4; ++r)
                scr[(g * 4 + r) * SW + ni * 16 + l15] = acc[mi][ni][r] + bb;
        }
#pragma unroll
        for (int it = 0; it < 4; ++it) {
            const int flat = it * 64 + lane;   // 0..255
            const int row  = flat >> 4;        // 0..15
            const int c4   = flat & 15;
            f32x4_t v = *reinterpret_cast<const f32x4_t*>(&scr[row * SW + c4 * 4]);
            float* yp = Y + (rowbase + mi * 16 + row) * 512 + colbase + c4 * 4;
            __builtin_nontemporal_store(v, reinterpret_cast<f32x4_t*>(yp));
        }
    }
}

extern "C" void kernel_launch(void* const* d_in, const int* in_sizes, int n_in,
                              void* d_out, int out_size, void* d_ws, size_t ws_size,
                              hipStream_t stream) {
    const float* x     = (const float*)d_in[0];
    const float* basis = (const float*)d_in[1];
    const float* adj   = (const float*)d_in[2];
    const float* e     = (const float*)d_in[3];
    const float* We    = (const float*)d_in[4];
    const float* W2    = (const float*)d_in[5];
    const float* W3    = (const float*)d_in[6];
    const float* bias  = (const float*)d_in[7];

    unsigned short* Mfrag = (unsigned short*)d_ws;  // 512 KB needed
    if (ws_size < 512u * 512u * 2u) return;

    const int Bsz = in_sizes[0] / 512;              // 131072
    build_M_kernel<<<512, 512, 0, stream>>>(basis, adj, e, We, W2, W3, Mfrag);
    gemm_kernel<<<Bsz / 64, 512, 0, stream>>>(x, Mfrag, bias, (float*)d_out);
}

// Round 11
// 141.228 us; speedup vs baseline: 1.0404x; 1.0286x over previous
//
#include <hip/hip_runtime.h>
#include <hip/hip_bf16.h>

typedef __attribute__((ext_vector_type(4))) float f32x4_t;
typedef __attribute__((ext_vector_type(8))) short bf16x8_t;

__device__ __forceinline__ short f2bfs(float x) {
    union { __hip_bfloat16 h; short s; } u;
    u.h = __float2bfloat16(x);   // RNE
    return u.s;
}

__device__ __forceinline__ void gload_lds16(const float* g, float* l) {
    __builtin_amdgcn_global_load_lds(
        (const __attribute__((address_space(1))) void*)g,
        (__attribute__((address_space(3))) void*)l, 16, 0, 0);
}

// ---------------------------------------------------------------------------
// Kernel 1: build fused 512x512 operator M in fragment-major bf16 layout.
//   c = m*32+o (output col of GEMM), k = n2*32+f (contraction index)
//   M[c][k] = diag[m] * sum_{n,m2} basis[m,n] * Wbig[o,n,f,m2] * basis[n2,m2]
// B-fragment layout for mfma_f32_16x16x32_bf16:
//   flat ushort idx = ((ks*32 + c16)*64 + lane)*8 + j
//   value = M[c16*16 + (lane&15)][ks*32 + (lane>>4)*8 + j]
// ---------------------------------------------------------------------------
__global__ void build_M_kernel(const float* __restrict__ basis,
                               const float* __restrict__ adj,
                               const float* __restrict__ e,
                               const float* __restrict__ We,
                               const float* __restrict__ W2,
                               const float* __restrict__ W3,
                               unsigned short* __restrict__ Mfrag) {
    const int t = blockIdx.x * blockDim.x + threadIdx.x;  // 0..262143
    const int c = t >> 9;           // 0..511
    const int k = t & 511;
    const int m  = c >> 5, o = c & 31;
    const int n2 = k >> 5, f = k & 31;

    float lv[16];
    float mx = -3.4e38f;
#pragma unroll
    for (int j = 0; j < 16; ++j) {
        float a = adj[m * 16 + j];
        float v = (a > 0.0f) ? e[m * 16 + j] : -9.0e15f;
        lv[j] = v;
        mx = fmaxf(mx, v);
    }
    float s = 0.0f;
#pragma unroll
    for (int j = 0; j < 16; ++j) s += expf(lv[j] - mx);
    const float dg = expf(lv[m] - mx) / s;

    float acc = 0.0f;
#pragma unroll
    for (int n = 0; n < 10; ++n) {
        float t2 = 0.0f;
#pragma unroll
        for (int m2 = 0; m2 < 10; ++m2)
            t2 += We[(o * 10 + n) * 320 + f * 10 + m2] * basis[n2 * 16 + m2];
        acc += basis[m * 16 + n] * t2;
    }
#pragma unroll
    for (int n = 0; n < 3; ++n) {
        float t2 = 0.0f;
#pragma unroll
        for (int m2 = 0; m2 < 3; ++m2)
            t2 += W2[(o * 3 + n) * 96 + f * 3 + m2] * basis[n2 * 16 + 10 + m2];
        acc += basis[m * 16 + 10 + n] * t2;
    }
#pragma unroll
    for (int n = 0; n < 3; ++n) {
        float t2 = 0.0f;
#pragma unroll
        for (int m2 = 0; m2 < 3; ++m2)
            t2 += W3[(o * 3 + n) * 96 + f * 3 + m2] * basis[n2 * 16 + 13 + m2];
        acc += basis[m * 16 + 13 + n] * t2;
    }

    const float Mv = dg * acc;

    const int ks = k >> 5;
    const int g  = (k >> 3) & 3;
    const int j  = k & 7;
    const int idx = ((ks * 32 + (c >> 4)) * 64 + ((c & 15) + 16 * g)) * 8 + j;
    Mfrag[idx] = (unsigned short)f2bfs(Mv);
}

// ---------------------------------------------------------------------------
// Kernel 2: Y[131072 x 512] = X[131072 x 512] @ M^T + bias
// EXACTLY the R2/R3 champion structure (kernel C, 140.8 us): BM=32, grid
// 4096, DMA A-staging (global_load_lds w16, XOR-unit swizzle via pre-
// swizzled global source), barrier-free 16-step K-loop (B JIT from
// L2-resident Mfrag, in-loop cvt), per-wave LDS-transpose epilogue.
// ONE change: K-loop START ROTATION — ks0 = (blockIdx*5 + wave*2) & 15,
// loop ks = (ks0+i)&15. Every block/wave previously traversed B in the
// same ks order, so the whole chip hammered the SAME 32 KB B-slab in L2
// at any instant (fully correlated streams -> inflated L2 latency,
// correlated wave stalls). Rotation spreads reads over all 16 slabs.
// Only the f32-accumulation order changes (margin 4x under threshold).
// ---------------------------------------------------------------------------
__global__ __launch_bounds__(512, 4)
void gemm_kernel(const float* __restrict__ X,
                 const unsigned short* __restrict__ Mfrag,
                 const float* __restrict__ bias,
                 float* __restrict__ Y) {
    __shared__ float Atile[32 * 512];   // 64 KB

    const int tid  = threadIdx.x;
    const int lane = tid & 63;
    const int wave = tid >> 6;        // 0..7
    const int l15  = lane & 15;
    const int g    = lane >> 4;       // 0..3
    const size_t rowbase = (size_t)blockIdx.x * 32;

    // ---- Stage: 8 async DMA loads per wave, 1 KB each ----
    {
        const float* xb = X + rowbase * 512;
#pragma unroll
        for (int i = 0; i < 8; ++i) {
            const int row  = wave * 4 + (i >> 1);
            const int half = i & 1;
            // LDS dest: wave-uniform base, HW adds lane*16 -> phys chunk half*64+lane
            float* ldst = &Atile[row * 512 + half * 256];
            // logical k4 = phys k4 ^ (row&7)  (XOR swizzle via global src)
            const int lk4 = (half * 64 + lane) ^ (row & 7);
            gload_lds16(xb + row * 512 + lk4 * 4, ldst);
        }
    }
    __syncthreads();

    // ---- K-loop (rotated start; no barriers) ----
    const int colbase = wave * 64;
    const unsigned short* bp = Mfrag + ((size_t)((colbase >> 4) * 64) + lane) * 8;
    const int s = l15 & 7;            // row&7 for both mi (rows mi*16+l15)
    const int ks0 = ((int)blockIdx.x * 5 + wave * 2) & 15;

    f32x4_t acc[2][4];
#pragma unroll
    for (int a = 0; a < 2; ++a)
#pragma unroll
        for (int b = 0; b < 4; ++b)
            acc[a][b] = (f32x4_t){0.f, 0.f, 0.f, 0.f};

#pragma unroll 4
    for (int i = 0; i < 16; ++i) {
        const int ks = (ks0 + i) & 15;
        bf16x8_t bfr[4];
#pragma unroll
        for (int ni = 0; ni < 4; ++ni)
            bfr[ni] = *reinterpret_cast<const bf16x8_t*>(bp + (size_t)ks * 16384 + ni * 512);

        bf16x8_t a[2];
#pragma unroll
        for (int mi = 0; mi < 2; ++mi) {
            const int row = mi * 16 + l15;
            const int pl  = ks * 8 + ((g * 2) ^ s);
            const int ph  = ks * 8 + ((g * 2 + 1) ^ s);
            f32x4_t lo = *reinterpret_cast<const f32x4_t*>(&Atile[row * 512 + pl * 4]);
            f32x4_t hi = *reinterpret_cast<const f32x4_t*>(&Atile[row * 512 + ph * 4]);
#pragma unroll
            for (int j = 0; j < 4; ++j) {
                a[mi][j]     = f2bfs(lo[j]);
                a[mi][j + 4] = f2bfs(hi[j]);
            }
        }
#pragma unroll
        for (int mi = 0; mi < 2; ++mi)
#pragma unroll
            for (int ni = 0; ni < 4; ++ni)
                acc[mi][ni] = __builtin_amdgcn_mfma_f32_16x16x32_bf16(
                    a[mi], bfr[ni], acc[mi][ni], 0, 0, 0);
    }

    __syncthreads();   // all waves done reading Atile

    // ---- Epilogue: per-wave transpose through LDS, then 256B NT stores ----
    // scratch: 32 rows x 64 cols f32 per wave (8 KB), reusing Atile
    float* scr = Atile + wave * 2048;
    const float b_lo = bias[l15];
    const float b_hi = bias[16 + l15];

#pragma unroll
    for (int mi = 0; mi < 2; ++mi)
#pragma unroll
        for (int ni = 0; ni < 4; ++ni) {
            const float bb = (ni & 1) ? b_hi : b_lo;
#pragma unroll
            for (int r = 0; r < 4; ++r)
                scr[(mi * 16 + g * 4 + r) * 64 + ni * 16 + l15] = acc[mi][ni][r] + bb;
        }

#pragma unroll
    for (int it = 0; it < 8; ++it) {
        const int flat = it * 64 + lane;       // 0..511
        const int row  = flat >> 4;            // 0..31
        const int c4   = flat & 15;
        f32x4_t v = *reinterpret_cast<const f32x4_t*>(&scr[row * 64 + c4 * 4]);
        float* yp = Y + (rowbase + row) * 512 + colbase + c4 * 4;
        __builtin_nontemporal_store(v, reinterpret_cast<f32x4_t*>(yp));
    }
}

extern "C" void kernel_launch(void* const* d_in, const int* in_sizes, int n_in,
                              void* d_out, int out_size, void* d_ws, size_t ws_size,
                              hipStream_t stream) {
    const float* x     = (const float*)d_in[0];
    const float* basis = (const float*)d_in[1];
    const float* adj   = (const float*)d_in[2];
    const float* e     = (const float*)d_in[3];
    const float* We    = (const float*)d_in[4];
    const float* W2    = (const float*)d_in[5];
    const float* W3    = (const float*)d_in[6];
    const float* bias  = (const float*)d_in[7];

    unsigned short* Mfrag = (unsigned short*)d_ws;  // 512 KB needed
    if (ws_size < 512u * 512u * 2u) return;

    const int Bsz = in_sizes[0] / 512;              // 131072
    build_M_kernel<<<512, 512, 0, stream>>>(basis, adj, e, We, W2, W3, Mfrag);
    gemm_kernel<<<Bsz / 32, 512, 0, stream>>>(x, Mfrag, bias, (float*)d_out);
}